// Round 1
// baseline (461.390 us; speedup 1.0000x reference)
//
#include <hip/hip_runtime.h>

// ---------------- problem constants ----------------
// b=4, C=512, h=w=128, BH=BW=4 -> 64 instances, P=1024 pixels each
// CM=76 (pad 80/96), mid=256
#define CM_    76
#define CMP_   80

typedef __attribute__((ext_vector_type(4))) float f32x4;
typedef __attribute__((ext_vector_type(8))) short bf16x8;

__device__ __forceinline__ unsigned short f2bf(float f) {
  union { float f; unsigned u; } v; v.f = f;
  unsigned r = v.u + 0x7FFFu + ((v.u >> 16) & 1u);
  return (unsigned short)(r >> 16);
}
__device__ __forceinline__ unsigned pack2(float a, float b) {
  return (unsigned)f2bf(a) | ((unsigned)f2bf(b) << 16);
}

// ---------------- workspace layout (float offsets; all 16B-aligned) ----------------
#define OFF_BK2     0            // [64][80] f32 (init cbb / -1e30 pads, k2 atomics add)
#define OFF_INV     5120         // [512] f32
#define OFF_ADD     5632         // [512] f32
#define OFF_WKBQ    6144         // [512] f32  (Wk@bq)
#define OFF_BQKADD  6656         // [512] f32  (Wq@bk)
#define OFF_CBB     7168         // [1] f32 (pad to 7172)
#define OFF_EXPSIM  7172         // bf16 [64][80][1024]  (2,621,440 f)
#define OFF_LOCALBF 2628612      // bf16 [64][80][512]   (1,310,720 f)
#define OFF_WQKT    3939332      // bf16 [64][80][512]
#define OFF_VWT     5250052      // bf16 [512][96]
#define OFF_WQWKT   5274628      // bf16 [512][512] (Wq@Wk^T)
#define OFF_WVWCT   5405700      // bf16 [512][512] (Wc^T@Wv^T)
// total 5,536,772 floats = 22.1 MB

// ---------------- kW (one-off): WqWkT / WvWcT + (blk.x==64) scalar pre ----------------
// grid (65, 2)
__global__ __launch_bounds__(256) void kW_pre(
    const float* __restrict__ Wq, const float* __restrict__ Wk,
    const float* __restrict__ Wv, const float* __restrict__ Wc,
    const float* __restrict__ bq, const float* __restrict__ bk,
    const float* __restrict__ gamma, const float* __restrict__ beta,
    const float* __restrict__ mean, const float* __restrict__ var,
    unsigned short* __restrict__ WqWkT, unsigned short* __restrict__ WvWcT,
    float* __restrict__ wkbq, float* __restrict__ bqkadd,
    float* __restrict__ invp, float* __restrict__ addp, float* __restrict__ cbbp) {
  const int sel = blockIdx.y;
  if (blockIdx.x == 64) {       // scalar pre-kernel half (c = sel*256 + t)
    const int c = sel * 256 + threadIdx.x;
    const float* wkr = Wk + (size_t)c * 256;
    const float* wqr = Wq + (size_t)c * 256;
    float s1 = 0.f, s2 = 0.f;
    for (int m = 0; m < 256; ++m) { s1 += wkr[m] * bq[m]; s2 += wqr[m] * bk[m]; }
    wkbq[c] = s1; bqkadd[c] = s2;
    float iv = gamma[c] * rsqrtf(var[c] + 1e-5f);
    invp[c] = iv; addp[c] = beta[c] - mean[c] * iv;
    if (c == 0) {
      float s = 0.f;
      for (int m = 0; m < 256; ++m) s += bq[m] * bk[m];
      cbbp[0] = s;
    }
    return;
  }
  const int r0 = (blockIdx.x >> 3) * 64, c0 = (blockIdx.x & 7) * 64;
  __shared__ __align__(16) unsigned short Asm[64 * 40];
  __shared__ __align__(16) unsigned short Bsm[64 * 40];
  const int t = threadIdx.x, lane = t & 63, w = t >> 6;
  const int lo = lane & 15, hi = lane >> 4;
  f32x4 acc[4];
#pragma unroll
  for (int cT = 0; cT < 4; ++cT) acc[cT] = (f32x4){0.f, 0.f, 0.f, 0.f};
  const float* Bsrc = sel ? Wv : Wk;
  for (int kc = 0; kc < 8; ++kc) {
    const int k0 = kc * 32;
    __syncthreads();
    {
      int nn = t >> 2, mq = (t & 3) * 8;
      const float* src = Bsrc + (size_t)(c0 + nn) * 256 + k0 + mq;
      float4 v0 = *(const float4*)src, v1 = *(const float4*)(src + 4);
      unsigned* d = (unsigned*)&Bsm[nn * 40 + mq];
      d[0] = pack2(v0.x, v0.y); d[1] = pack2(v0.z, v0.w);
      d[2] = pack2(v1.x, v1.y); d[3] = pack2(v1.z, v1.w);
    }
    if (sel == 0) {
      int r = t >> 2, mq = (t & 3) * 8;
      const float* src = Wq + (size_t)(r0 + r) * 256 + k0 + mq;
      float4 v0 = *(const float4*)src, v1 = *(const float4*)(src + 4);
      unsigned* d = (unsigned*)&Asm[r * 40 + mq];
      d[0] = pack2(v0.x, v0.y); d[1] = pack2(v0.z, v0.w);
      d[2] = pack2(v1.x, v1.y); d[3] = pack2(v1.z, v1.w);
    } else {
      int m = t >> 3, c2q = (t & 7) * 8;
      const float* src = Wc + (size_t)(k0 + m) * 512 + r0 + c2q;
      float4 v0 = *(const float4*)src, v1 = *(const float4*)(src + 4);
      Asm[(c2q + 0) * 40 + m] = f2bf(v0.x); Asm[(c2q + 1) * 40 + m] = f2bf(v0.y);
      Asm[(c2q + 2) * 40 + m] = f2bf(v0.z); Asm[(c2q + 3) * 40 + m] = f2bf(v0.w);
      Asm[(c2q + 4) * 40 + m] = f2bf(v1.x); Asm[(c2q + 5) * 40 + m] = f2bf(v1.y);
      Asm[(c2q + 6) * 40 + m] = f2bf(v1.z); Asm[(c2q + 7) * 40 + m] = f2bf(v1.w);
    }
    __syncthreads();
    bf16x8 afr = *(bf16x8*)(&Asm[(w * 16 + lo) * 40 + hi * 8]);
#pragma unroll
    for (int cT = 0; cT < 4; ++cT) {
      bf16x8 bfr = *(bf16x8*)(&Bsm[(cT * 16 + lo) * 40 + hi * 8]);
      acc[cT] = __builtin_amdgcn_mfma_f32_16x16x32_bf16(afr, bfr, acc[cT], 0, 0, 0);
    }
  }
  unsigned short* dst = sel ? WvWcT : WqWkT;
#pragma unroll
  for (int cT = 0; cT < 4; ++cT)
#pragma unroll
    for (int rr = 0; rr < 4; ++rr)
      dst[(size_t)(r0 + w * 16 + hi * 4 + rr) * 512 + c0 + cT * 16 + lo] = f2bf(acc[cT][rr]);
}

// ---------------- K1: stats + materialize expsim bf16 (scaled), init bk2 ----------------
// grid (80, 64), block 256
__global__ __launch_bounds__(256) void k1_stats(
    const float* __restrict__ sim, float* __restrict__ pcs,
    const float* __restrict__ cbbp,
    unsigned short* __restrict__ expsim, float* __restrict__ bk2) {
  const int cm = blockIdx.x, inst = blockIdx.y;
  const int t = threadIdx.x;
  unsigned short* erow = expsim + (size_t)inst * 81920 + (size_t)cm * 1024;
  if (cm >= CM_) {                          // pad rows: zero, bk2 = -inf
    ((unsigned long long*)erow)[t] = 0ull;
    if (t == 0) bk2[inst * CMP_ + cm] = -1e30f;
    return;
  }
  const int b = inst >> 4, n = inst & 15, bh = n >> 2, bw = n & 3;
  const float* base = sim + ((size_t)(b * CM_ + cm) << 14);
  float v[4];
  float lsum = 0.f, lmax = -1e30f;
#pragma unroll
  for (int i = 0; i < 4; ++i) {
    int p = t + (i << 8);
    int pix = ((bh * 32 + (p >> 5)) << 7) + bw * 32 + (p & 31);
    float xv = base[pix];
    v[i] = xv; lsum += xv; lmax = fmaxf(lmax, xv);
  }
#pragma unroll
  for (int off = 32; off; off >>= 1) {
    lsum += __shfl_down(lsum, off);
    lmax = fmaxf(lmax, __shfl_down(lmax, off));
  }
  __shared__ float ssum[4], smax[4], bc[2];
  const int wid = t >> 6;
  if ((t & 63) == 0) { ssum[wid] = lsum; smax[wid] = lmax; }
  __syncthreads();
  if (t == 0) {
    bc[0] = ssum[0] + ssum[1] + ssum[2] + ssum[3];
    bc[1] = fmaxf(fmaxf(smax[0], smax[1]), fmaxf(smax[2], smax[3]));
  }
  __syncthreads();
  const float M = bc[1];
  float le = 0.f;
#pragma unroll
  for (int i = 0; i < 4; ++i) le += __expf(v[i] - M);
#pragma unroll
  for (int off = 32; off; off >>= 1) le += __shfl_down(le, off);
  if ((t & 63) == 0) ssum[wid] = le;
  __syncthreads();
  if (t == 0) {
    float E = ssum[0] + ssum[1] + ssum[2] + ssum[3];
    float conf = bc[0] * (1.f / 1024.f);
    pcs[((b * CM_ + cm) << 4) + n] = conf;
    bk2[inst * CMP_ + cm] = cbbp[0];        // base for k2's atomic accumulation
    bc[0] = conf / E;                        // broadcast scale
  }
  __syncthreads();
  const float sc = bc[0];
#pragma unroll
  for (int i = 0; i < 4; ++i) {
    int p = t + (i << 8);
    erow[p] = f2bf(sc * __expf(v[i] - M));
  }
}

// ---------------- K2 (MFMA, no LDS-stage): local bf16 = expsim @ x^T ; bk2 += local.wkbq ----------------
// grid (8, 64), block 1024: 16 waves = 4 ch-groups (16 ch each) x 4 K-quarters (256 px each).
// Was 256-thr / full-K per wave -> 2 waves/SIMD, latency-starved (Occupancy 18%, all pipes <18%).
// 4-way in-block K-split + LDS partial reduce -> 8 waves/SIMD potential (VGPR<=64, LDS 60KB -> 2 blk/CU).
__global__ __launch_bounds__(1024, 8) void k2_local(
    const float* __restrict__ x, const unsigned short* __restrict__ expsim,
    const float* __restrict__ wkbq,
    unsigned short* __restrict__ local_bf, float* __restrict__ bk2) {
  const int cc = blockIdx.x, inst = blockIdx.y;
  const int b = inst >> 4, n = inst & 15, bh = n >> 2, bw = n & 3;
  const int t = threadIdx.x, lane = t & 63, w = t >> 6;
  const int g = w & 3, kh = w >> 2;          // channel-group, K-quarter
  const int lo = lane & 15, hi = lane >> 4;
  const int chw = cc * 64 + g * 16;
  const unsigned short* Abase = expsim + (size_t)inst * 81920;
  const float* xch = x + (((size_t)(b * 512 + chw + lo)) << 14) + bw * 32 + hi * 8;
  const int rowb = bh * 32;
  // [kh-1][g][T][r][lane] : lane-contiguous f32 -> conflict-free b32 LDS ops. 60 KB.
  __shared__ float red[3][4][5][4][64];
  f32x4 acc[5];
#pragma unroll
  for (int T = 0; T < 5; ++T) acc[T] = (f32x4){0.f, 0.f, 0.f, 0.f};
#pragma unroll 4
  for (int ks = kh * 8; ks < kh * 8 + 8; ++ks) {
    const int k = ks * 32 + hi * 8;           // global patch-linear px
    const float* xr = xch + ((size_t)(rowb + ks) << 7);
    float4 v0 = *(const float4*)(xr);
    float4 v1 = *(const float4*)(xr + 4);
    bf16x8 bfr;
    ((unsigned*)&bfr)[0] = pack2(v0.x, v0.y);
    ((unsigned*)&bfr)[1] = pack2(v0.z, v0.w);
    ((unsigned*)&bfr)[2] = pack2(v1.x, v1.y);
    ((unsigned*)&bfr)[3] = pack2(v1.z, v1.w);
#pragma unroll
    for (int T = 0; T < 5; ++T) {
      bf16x8 afr = *(const bf16x8*)(Abase + (size_t)(T * 16 + lo) * 1024 + k);
      acc[T] = __builtin_amdgcn_mfma_f32_16x16x32_bf16(afr, bfr, acc[T], 0, 0, 0);
    }
  }
  if (kh) {
#pragma unroll
    for (int T = 0; T < 5; ++T)
#pragma unroll
      for (int r = 0; r < 4; ++r) red[kh - 1][g][T][r][lane] = acc[T][r];
  }
  __syncthreads();
  if (kh == 0) {
#pragma unroll
    for (int T = 0; T < 5; ++T)
#pragma unroll
      for (int r = 0; r < 4; ++r)
        acc[T][r] += red[0][g][T][r][lane] + red[1][g][T][r][lane] + red[2][g][T][r][lane];
    // epilogue: write local (pads exact 0), fold bk2 dot via lane-reduce + atomic
    const float wk = wkbq[chw + lo];
#pragma unroll
    for (int T = 0; T < 5; ++T)
#pragma unroll
      for (int r = 0; r < 4; ++r) {
        int cm = T * 16 + hi * 4 + r;
        float av = acc[T][r];
        local_bf[((size_t)inst * CMP_ + cm) * 512 + chw + lo] = f2bf(av);
        float p = av * wk;
        p += __shfl_xor(p, 1); p += __shfl_xor(p, 2);
        p += __shfl_xor(p, 4); p += __shfl_xor(p, 8);
        if (lo == 0 && cm < CM_) atomicAdd(&bk2[inst * CMP_ + cm], p);
      }
  }
}

// ---------------- k3n (MFMA): Wqkt[inst][cm][c] = local@WqWkT^T + bqkadd ----------------
// grid (8, 64): was (4,64) with 32 ch/wave = 1 wave/SIMD. Now 16 ch/wave, 2x blocks -> 2 waves/SIMD.
__global__ __launch_bounds__(256) void k3n_wqkt(
    const unsigned short* __restrict__ local_bf, const unsigned short* __restrict__ WqWkT,
    const float* __restrict__ bqkadd, unsigned short* __restrict__ Wqkt) {
  const int blkc = blockIdx.x, inst = blockIdx.y;
  const int t = threadIdx.x, lane = t & 63, w = t >> 6;
  const int lo = lane & 15, hi = lane >> 4;
  const int cbase = blkc * 64 + w * 16;
  f32x4 acc[5];
  {
    float bv_ = bqkadd[cbase + lo];
#pragma unroll
    for (int T = 0; T < 5; ++T) acc[T] = (f32x4){bv_, bv_, bv_, bv_};
  }
  const unsigned short* Abase = local_bf + (size_t)inst * 40960;
#pragma unroll 4
  for (int ks = 0; ks < 16; ++ks) {
    const int k = ks * 32 + hi * 8;
    bf16x8 bfr = *(const bf16x8*)(WqWkT + (size_t)(cbase + lo) * 512 + k);
#pragma unroll
    for (int T = 0; T < 5; ++T) {
      bf16x8 af = *(const bf16x8*)(Abase + (size_t)(T * 16 + lo) * 512 + k);
      acc[T] = __builtin_amdgcn_mfma_f32_16x16x32_bf16(af, bfr, acc[T], 0, 0, 0);
    }
  }
#pragma unroll
  for (int T = 0; T < 5; ++T)
#pragma unroll
    for (int r = 0; r < 4; ++r) {
      int cm = T * 16 + hi * 4 + r;
      Wqkt[(size_t)inst * 40960 + (size_t)cm * 512 + cbase + lo] = f2bf(acc[T][r]);
    }
}

// ---------------- kV (MFMA): vWt[c2][cm] = WvWcT@g^T + bvWc ----------------
// grid (8, 2)
__global__ __launch_bounds__(256) void kV_vwt(
    const unsigned short* __restrict__ WvWcT, const float* __restrict__ g,
    const float* __restrict__ bv, const float* __restrict__ Wc,
    unsigned short* __restrict__ vWt) {
  const int blk = blockIdx.x, half = blockIdx.y;
  const int t = threadIdx.x, lane = t & 63, w = t >> 6;
  const int lo = lane & 15, hi = lane >> 4;
  __shared__ float bvp[4][64];
  __shared__ float bvs[64];
  {
    int c2l = t & 63, part = t >> 6;
    float s = 0.f;
    for (int m = part * 64; m < part * 64 + 64; ++m)
      s += bv[m] * Wc[(size_t)m * 512 + blk * 64 + c2l];
    bvp[part][c2l] = s;
  }
  __syncthreads();
  if (t < 64) bvs[t] = bvp[0][t] + bvp[1][t] + bvp[2][t] + bvp[3][t];
  __syncthreads();
  const int r2 = blk * 64 + w * 16;
  f32x4 acc[3];
#pragma unroll
  for (int j = 0; j < 3; ++j) acc[j] = (f32x4){0.f, 0.f, 0.f, 0.f};
#pragma unroll 4
  for (int ks = 0; ks < 16; ++ks) {
    const int k = ks * 32 + hi * 8;
    bf16x8 afr = *(const bf16x8*)(WvWcT + (size_t)(r2 + lo) * 512 + k);
#pragma unroll
    for (int j = 0; j < 3; ++j) {
      int cm = (half * 3 + j) * 16 + lo;
      cm = cm > 75 ? 75 : cm;
      const float* gr = g + (size_t)cm * 512 + k;
      float4 v0 = *(const float4*)gr, v1 = *(const float4*)(gr + 4);
      bf16x8 bfr;
      ((unsigned*)&bfr)[0] = pack2(v0.x, v0.y);
      ((unsigned*)&bfr)[1] = pack2(v0.z, v0.w);
      ((unsigned*)&bfr)[2] = pack2(v1.x, v1.y);
      ((unsigned*)&bfr)[3] = pack2(v1.z, v1.w);
      acc[j] = __builtin_amdgcn_mfma_f32_16x16x32_bf16(afr, bfr, acc[j], 0, 0, 0);
    }
  }
#pragma unroll
  for (int j = 0; j < 3; ++j)
#pragma unroll
    for (int rr = 0; rr < 4; ++rr) {
      int c2g = blk * 64 + w * 16 + hi * 4 + rr;
      vWt[(size_t)c2g * 96 + (half * 3 + j) * 16 + lo] =
          f2bf(acc[j][rr] + bvs[w * 16 + hi * 4 + rr]);
    }
}

// ---------------- K4 (MFMA): logits -> in-register softmax -> y (BN+ReLU) ----------------
// grid (8, 64)
__global__ __launch_bounds__(256) void k4_attn(
    const float* __restrict__ x, const unsigned short* __restrict__ Wqkt,
    const float* __restrict__ bk2, const unsigned short* __restrict__ vWt,
    const float* __restrict__ inv_arr, const float* __restrict__ add_arr,
    float* __restrict__ y) {
  const int pt = blockIdx.x, inst = blockIdx.y;
  const int b = inst >> 4, n = inst & 15, bh = n >> 2, bw = n & 3;
  __shared__ unsigned short Xs[4][32 * 72];
  __shared__ unsigned short Att[4][32 * 96];
  __shared__ float bn_s[1024];
  const int t = threadIdx.x, lane = t & 63, w = t >> 6;
  const int lo = lane & 15, hi = lane >> 4;
  const int pq = lane & 7, chp0 = lane >> 3;

  for (int i = t; i < 512; i += 256) { bn_s[i] = inv_arr[i]; bn_s[512 + i] = add_arr[i]; }

  const int imgrow = bh * 32 + pt * 4 + w;
  const size_t pixbase = (size_t)imgrow * 128 + bw * 32;
  const size_t xrowbase = (((size_t)b * 512) << 14) + pixbase;
  const unsigned short* Wi = Wqkt + (size_t)inst * 40960;

  f32x4 acc[2][5];
#pragma unroll
  for (int T = 0; T < 5; ++T) {
    f32x4 bv;
#pragma unroll
    for (int r = 0; r < 4; ++r) bv[r] = bk2[inst * CMP_ + T * 16 + hi * 4 + r];
    acc[0][T] = bv; acc[1][T] = bv;
  }

  for (int kc = 0; kc < 8; ++kc) {
#pragma unroll
    for (int i = 0; i < 4; ++i) {
      int chp = chp0 + i * 8;
      int ch = kc * 64 + chp * 2;
      const float* xa = x + xrowbase + ((size_t)ch << 14) + pq * 4;
      float4 va = *(const float4*)(xa);
      float4 vb = *(const float4*)(xa + 16384);
      unsigned short* dst = &Xs[w][(pq * 4) * 72 + chp * 2];
      *(unsigned*)(dst + 0 * 72) = pack2(va.x, vb.x);
      *(unsigned*)(dst + 1 * 72) = pack2(va.y, vb.y);
      *(unsigned*)(dst + 2 * 72) = pack2(va.z, vb.z);
      *(unsigned*)(dst + 3 * 72) = pack2(va.w, vb.w);
    }
#pragma unroll
    for (int ks = 0; ks < 2; ++ks) {
      int kb = kc * 64 + ks * 32 + hi * 8;
      bf16x8 b0 = *(bf16x8*)(&Xs[w][lo * 72 + ks * 32 + hi * 8]);
      bf16x8 b1 = *(bf16x8*)(&Xs[w][(16 + lo) * 72 + ks * 32 + hi * 8]);
#pragma unroll
      for (int T = 0; T < 5; ++T) {
        bf16x8 afr = *(const bf16x8*)(Wi + (size_t)(T * 16 + lo) * 512 + kb);
        acc[0][T] = __builtin_amdgcn_mfma_f32_16x16x32_bf16(afr, b0, acc[0][T], 0, 0, 0);
        acc[1][T] = __builtin_amdgcn_mfma_f32_16x16x32_bf16(afr, b1, acc[1][T], 0, 0, 0);
      }
    }
  }

#pragma unroll
  for (int p = 0; p < 2; ++p) {
    float m = -1e30f;
#pragma unroll
    for (int T = 0; T < 5; ++T)
#pragma unroll
      for (int r = 0; r < 4; ++r) m = fmaxf(m, acc[p][T][r]);
    m = fmaxf(m, __shfl_xor(m, 16));
    m = fmaxf(m, __shfl_xor(m, 32));
    float e[5][4];
    float s = 0.f;
#pragma unroll
    for (int T = 0; T < 5; ++T)
#pragma unroll
      for (int r = 0; r < 4; ++r) { float ev = __expf(acc[p][T][r] - m); e[T][r] = ev; s += ev; }
    s += __shfl_xor(s, 16);
    s += __shfl_xor(s, 32);
    float rinv = 1.f / s;
    int px = p * 16 + lo;
#pragma unroll
    for (int T = 0; T < 5; ++T) {
      unsigned l32 = pack2(e[T][0] * rinv, e[T][1] * rinv);
      unsigned h32 = pack2(e[T][2] * rinv, e[T][3] * rinv);
      *(unsigned long long*)(&Att[w][px * 96 + T * 16 + hi * 4]) =
          (unsigned long long)l32 | ((unsigned long long)h32 << 32);
    }
    *(unsigned long long*)(&Att[w][px * 96 + 80 + hi * 4]) = 0ull;
  }

  __syncthreads();

  bf16x8 bfr3[2][3];
#pragma unroll
  for (int p = 0; p < 2; ++p)
#pragma unroll
    for (int ks = 0; ks < 3; ++ks)
      bfr3[p][ks] = *(bf16x8*)(&Att[w][(p * 16 + lo) * 96 + ks * 32 + hi * 8]);

  for (int cT = 0; cT < 32; ++cT) {
    f32x4 a0 = (f32x4){0.f, 0.f, 0.f, 0.f}, a1 = a0;
    const unsigned short* vr = vWt + (size_t)(cT * 16 + lo) * 96;
#pragma unroll
    for (int ks = 0; ks < 3; ++ks) {
      bf16x8 afr = *(const bf16x8*)(vr + ks * 32 + hi * 8);
      a0 = __builtin_amdgcn_mfma_f32_16x16x32_bf16(afr, bfr3[0][ks], a0, 0, 0, 0);
      a1 = __builtin_amdgcn_mfma_f32_16x16x32_bf16(afr, bfr3[1][ks], a1, 0, 0, 0);
    }
    f32x4 inv4 = *(f32x4*)(&bn_s[cT * 16 + hi * 4]);
    f32x4 add4 = *(f32x4*)(&bn_s[512 + cT * 16 + hi * 4]);
#pragma unroll
    for (int r = 0; r < 4; ++r) {
      int ch = cT * 16 + hi * 4 + r;
      float v0 = fmaxf(a0[r] * inv4[r] + add4[r], 0.f);
      float v1 = fmaxf(a1[r] * inv4[r] + add4[r], 0.f);
      size_t yb = (((size_t)(b * 512 + ch)) << 14) + pixbase;
      y[yb + lo] = v0;
      y[yb + 16 + lo] = v1;
    }
  }
}

// ---------------- host launch ----------------
extern "C" void kernel_launch(void* const* d_in, const int* in_sizes, int n_in,
                              void* d_out, int out_size, void* d_ws, size_t ws_size,
                              hipStream_t stream) {
  (void)in_sizes; (void)n_in; (void)out_size; (void)ws_size;
  const float* x     = (const float*)d_in[0];
  const float* sim   = (const float*)d_in[1];
  const float* g     = (const float*)d_in[2];
  const float* Wq    = (const float*)d_in[3];
  const float* bq    = (const float*)d_in[4];
  const float* Wk    = (const float*)d_in[5];
  const float* bk    = (const float*)d_in[6];
  const float* Wv    = (const float*)d_in[7];
  const float* bv    = (const float*)d_in[8];
  const float* Wc    = (const float*)d_in[9];
  const float* gamma = (const float*)d_in[10];
  const float* beta  = (const float*)d_in[11];
  const float* mean  = (const float*)d_in[12];
  const float* var   = (const float*)d_in[13];
  float* out = (float*)d_out;
  float* ws  = (float*)d_ws;
  float* y   = out;                    // [4][512][128][128]
  float* pcs = out + 33554432;         // [4][76][4][4]
  unsigned short* expsim  = (unsigned short*)(ws + OFF_EXPSIM);
  unsigned short* localbf = (unsigned short*)(ws + OFF_LOCALBF);
  unsigned short* Wqkt    = (unsigned short*)(ws + OFF_WQKT);
  unsigned short* vWt     = (unsigned short*)(ws + OFF_VWT);
  unsigned short* WqWkT   = (unsigned short*)(ws + OFF_WQWKT);
  unsigned short* WvWcT   = (unsigned short*)(ws + OFF_WVWCT);

  hipLaunchKernelGGL(kW_pre, dim3(65, 2), dim3(256), 0, stream,
                     Wq, Wk, Wv, Wc, bq, bk, gamma, beta, mean, var,
                     WqWkT, WvWcT, ws + OFF_WKBQ, ws + OFF_BQKADD,
                     ws + OFF_INV, ws + OFF_ADD, ws + OFF_CBB);
  hipLaunchKernelGGL(k1_stats, dim3(CMP_, 64), dim3(256), 0, stream,
                     sim, pcs, ws + OFF_CBB, expsim, ws + OFF_BK2);
  hipLaunchKernelGGL(k2_local, dim3(8, 64), dim3(1024), 0, stream,
                     x, expsim, ws + OFF_WKBQ, localbf, ws + OFF_BK2);
  hipLaunchKernelGGL(k3n_wqkt, dim3(8, 64), dim3(256), 0, stream,
                     localbf, WqWkT, ws + OFF_BQKADD, Wqkt);
  hipLaunchKernelGGL(kV_vwt, dim3(8, 2), dim3(256), 0, stream,
                     WvWcT, g, bv, Wc, vWt);
  hipLaunchKernelGGL(k4_attn, dim3(8, 64), dim3(256), 0, stream,
                     x, Wqkt, ws + OFF_BK2, vWt,
                     ws + OFF_INV, ws + OFF_ADD, y);
}

// Round 2
// 431.988 us; speedup vs baseline: 1.0681x; 1.0681x over previous
//
#include <hip/hip_runtime.h>

// ---------------- problem constants ----------------
// b=4, C=512, h=w=128, BH=BW=4 -> 64 instances, P=1024 pixels each
// CM=76 (pad 80/96), mid=256
#define CM_    76
#define CMP_   80

typedef __attribute__((ext_vector_type(4))) float f32x4;
typedef __attribute__((ext_vector_type(8))) short bf16x8;

__device__ __forceinline__ unsigned short f2bf(float f) {
  union { float f; unsigned u; } v; v.f = f;
  unsigned r = v.u + 0x7FFFu + ((v.u >> 16) & 1u);
  return (unsigned short)(r >> 16);
}
__device__ __forceinline__ unsigned pack2(float a, float b) {
  return (unsigned)f2bf(a) | ((unsigned)f2bf(b) << 16);
}

// ---------------- workspace layout (float offsets; all 16B-aligned) ----------------
#define OFF_BK2     0            // [64][80] f32 (init cbb / -1e30 pads, k2 atomics add)
#define OFF_INV     5120         // [512] f32
#define OFF_ADD     5632         // [512] f32
#define OFF_WKBQ    6144         // [512] f32  (Wk@bq)
#define OFF_BQKADD  6656         // [512] f32  (Wq@bk)
#define OFF_CBB     7168         // [1] f32 (pad to 7172)
#define OFF_EXPSIM  7172         // bf16 [64][80][1024]  (2,621,440 f)
#define OFF_LOCALBF 2628612      // bf16 [64][80][512]   (1,310,720 f)
#define OFF_WQKT    3939332      // bf16 [64][80][512]
#define OFF_VWT     5250052      // bf16 [512][96]
#define OFF_WQWKT   5274628      // bf16 [512][512] (Wq@Wk^T)
#define OFF_WVWCT   5405700      // bf16 [512][512] (Wc^T@Wv^T)
// total 5,536,772 floats = 22.1 MB

// ---------------- kW (one-off): WqWkT / WvWcT + (blk.x==64) scalar pre ----------------
// grid (65, 2)
__global__ __launch_bounds__(256) void kW_pre(
    const float* __restrict__ Wq, const float* __restrict__ Wk,
    const float* __restrict__ Wv, const float* __restrict__ Wc,
    const float* __restrict__ bq, const float* __restrict__ bk,
    const float* __restrict__ gamma, const float* __restrict__ beta,
    const float* __restrict__ mean, const float* __restrict__ var,
    unsigned short* __restrict__ WqWkT, unsigned short* __restrict__ WvWcT,
    float* __restrict__ wkbq, float* __restrict__ bqkadd,
    float* __restrict__ invp, float* __restrict__ addp, float* __restrict__ cbbp) {
  const int sel = blockIdx.y;
  if (blockIdx.x == 64) {       // scalar pre-kernel half (c = sel*256 + t)
    const int c = sel * 256 + threadIdx.x;
    const float* wkr = Wk + (size_t)c * 256;
    const float* wqr = Wq + (size_t)c * 256;
    float s1 = 0.f, s2 = 0.f;
    for (int m = 0; m < 256; ++m) { s1 += wkr[m] * bq[m]; s2 += wqr[m] * bk[m]; }
    wkbq[c] = s1; bqkadd[c] = s2;
    float iv = gamma[c] * rsqrtf(var[c] + 1e-5f);
    invp[c] = iv; addp[c] = beta[c] - mean[c] * iv;
    if (c == 0) {
      float s = 0.f;
      for (int m = 0; m < 256; ++m) s += bq[m] * bk[m];
      cbbp[0] = s;
    }
    return;
  }
  const int r0 = (blockIdx.x >> 3) * 64, c0 = (blockIdx.x & 7) * 64;
  __shared__ __align__(16) unsigned short Asm[64 * 40];
  __shared__ __align__(16) unsigned short Bsm[64 * 40];
  const int t = threadIdx.x, lane = t & 63, w = t >> 6;
  const int lo = lane & 15, hi = lane >> 4;
  f32x4 acc[4];
#pragma unroll
  for (int cT = 0; cT < 4; ++cT) acc[cT] = (f32x4){0.f, 0.f, 0.f, 0.f};
  const float* Bsrc = sel ? Wv : Wk;
  for (int kc = 0; kc < 8; ++kc) {
    const int k0 = kc * 32;
    __syncthreads();
    {
      int nn = t >> 2, mq = (t & 3) * 8;
      const float* src = Bsrc + (size_t)(c0 + nn) * 256 + k0 + mq;
      float4 v0 = *(const float4*)src, v1 = *(const float4*)(src + 4);
      unsigned* d = (unsigned*)&Bsm[nn * 40 + mq];
      d[0] = pack2(v0.x, v0.y); d[1] = pack2(v0.z, v0.w);
      d[2] = pack2(v1.x, v1.y); d[3] = pack2(v1.z, v1.w);
    }
    if (sel == 0) {
      int r = t >> 2, mq = (t & 3) * 8;
      const float* src = Wq + (size_t)(r0 + r) * 256 + k0 + mq;
      float4 v0 = *(const float4*)src, v1 = *(const float4*)(src + 4);
      unsigned* d = (unsigned*)&Asm[r * 40 + mq];
      d[0] = pack2(v0.x, v0.y); d[1] = pack2(v0.z, v0.w);
      d[2] = pack2(v1.x, v1.y); d[3] = pack2(v1.z, v1.w);
    } else {
      int m = t >> 3, c2q = (t & 7) * 8;
      const float* src = Wc + (size_t)(k0 + m) * 512 + r0 + c2q;
      float4 v0 = *(const float4*)src, v1 = *(const float4*)(src + 4);
      Asm[(c2q + 0) * 40 + m] = f2bf(v0.x); Asm[(c2q + 1) * 40 + m] = f2bf(v0.y);
      Asm[(c2q + 2) * 40 + m] = f2bf(v0.z); Asm[(c2q + 3) * 40 + m] = f2bf(v0.w);
      Asm[(c2q + 4) * 40 + m] = f2bf(v1.x); Asm[(c2q + 5) * 40 + m] = f2bf(v1.y);
      Asm[(c2q + 6) * 40 + m] = f2bf(v1.z); Asm[(c2q + 7) * 40 + m] = f2bf(v1.w);
    }
    __syncthreads();
    bf16x8 afr = *(bf16x8*)(&Asm[(w * 16 + lo) * 40 + hi * 8]);
#pragma unroll
    for (int cT = 0; cT < 4; ++cT) {
      bf16x8 bfr = *(bf16x8*)(&Bsm[(cT * 16 + lo) * 40 + hi * 8]);
      acc[cT] = __builtin_amdgcn_mfma_f32_16x16x32_bf16(afr, bfr, acc[cT], 0, 0, 0);
    }
  }
  unsigned short* dst = sel ? WvWcT : WqWkT;
#pragma unroll
  for (int cT = 0; cT < 4; ++cT)
#pragma unroll
    for (int rr = 0; rr < 4; ++rr)
      dst[(size_t)(r0 + w * 16 + hi * 4 + rr) * 512 + c0 + cT * 16 + lo] = f2bf(acc[cT][rr]);
}

// ---------------- K1: stats + materialize expsim bf16 (scaled), init bk2 ----------------
// grid (80, 64), block 256
__global__ __launch_bounds__(256) void k1_stats(
    const float* __restrict__ sim, float* __restrict__ pcs,
    const float* __restrict__ cbbp,
    unsigned short* __restrict__ expsim, float* __restrict__ bk2) {
  const int cm = blockIdx.x, inst = blockIdx.y;
  const int t = threadIdx.x;
  unsigned short* erow = expsim + (size_t)inst * 81920 + (size_t)cm * 1024;
  if (cm >= CM_) {                          // pad rows: zero, bk2 = -inf
    ((unsigned long long*)erow)[t] = 0ull;
    if (t == 0) bk2[inst * CMP_ + cm] = -1e30f;
    return;
  }
  const int b = inst >> 4, n = inst & 15, bh = n >> 2, bw = n & 3;
  const float* base = sim + ((size_t)(b * CM_ + cm) << 14);
  float v[4];
  float lsum = 0.f, lmax = -1e30f;
#pragma unroll
  for (int i = 0; i < 4; ++i) {
    int p = t + (i << 8);
    int pix = ((bh * 32 + (p >> 5)) << 7) + bw * 32 + (p & 31);
    float xv = base[pix];
    v[i] = xv; lsum += xv; lmax = fmaxf(lmax, xv);
  }
#pragma unroll
  for (int off = 32; off; off >>= 1) {
    lsum += __shfl_down(lsum, off);
    lmax = fmaxf(lmax, __shfl_down(lmax, off));
  }
  __shared__ float ssum[4], smax[4], bc[2];
  const int wid = t >> 6;
  if ((t & 63) == 0) { ssum[wid] = lsum; smax[wid] = lmax; }
  __syncthreads();
  if (t == 0) {
    bc[0] = ssum[0] + ssum[1] + ssum[2] + ssum[3];
    bc[1] = fmaxf(fmaxf(smax[0], smax[1]), fmaxf(smax[2], smax[3]));
  }
  __syncthreads();
  const float M = bc[1];
  float le = 0.f;
#pragma unroll
  for (int i = 0; i < 4; ++i) le += __expf(v[i] - M);
#pragma unroll
  for (int off = 32; off; off >>= 1) le += __shfl_down(le, off);
  if ((t & 63) == 0) ssum[wid] = le;
  __syncthreads();
  if (t == 0) {
    float E = ssum[0] + ssum[1] + ssum[2] + ssum[3];
    float conf = bc[0] * (1.f / 1024.f);
    pcs[((b * CM_ + cm) << 4) + n] = conf;
    bk2[inst * CMP_ + cm] = cbbp[0];        // base for k2's atomic accumulation
    bc[0] = conf / E;                        // broadcast scale
  }
  __syncthreads();
  const float sc = bc[0];
#pragma unroll
  for (int i = 0; i < 4; ++i) {
    int p = t + (i << 8);
    erow[p] = f2bf(sc * __expf(v[i] - M));
  }
}

// ---------------- K2 v3 (MFMA, explicit reg double-buffer): local = expsim @ x^T ----------------
// grid (4, 64), block 512 = 8 waves x 16 ch (128 ch/block). Full K per wave, no LDS.
// History: v1 (4 waves, 48 VGPR) = 88 us @ 1.37 TB/s - ILP-starved: compiler had no
//   registers to keep the 7 loads/iter in flight (waits vmcnt on x before issuing A-loads).
// v2 (16 waves, 32 VGPR, K-split) = 118 us - occupancy up but ILP down + 73 MB refetch.
// v3: 2-stage named register pipeline (prefetch ks+1 while MFMA'ing ks),
//   __launch_bounds__(512,4) -> 128 VGPR cap (~95 used). 4 blocks/inst halves
//   expsim refetch vs v1's 8. Target: >= 3 TB/s effective.
__global__ __launch_bounds__(512, 4) void k2_local(
    const float* __restrict__ x, const unsigned short* __restrict__ expsim,
    const float* __restrict__ wkbq,
    unsigned short* __restrict__ local_bf, float* __restrict__ bk2) {
  const int cc = blockIdx.x, inst = blockIdx.y;
  const int b = inst >> 4, n = inst & 15, bh = n >> 2, bw = n & 3;
  const int t = threadIdx.x, lane = t & 63, w = t >> 6;
  const int lo = lane & 15, hi = lane >> 4;
  const int chw = cc * 128 + w * 16;
  // A (expsim) per-lane row: (T*16+lo)*1024 + ks*32 + hi*8   (ushort units)
  const unsigned short* Arow = expsim + (size_t)inst * 81920 + (size_t)lo * 1024 + hi * 8;
  // B (x) per-lane: channel chw+lo, patch row bh*32+ks, pixel col bw*32 + hi*8
  const float* xch = x + (((size_t)(b * 512 + chw + lo)) << 14)
                       + (((size_t)(bh * 32)) << 7) + bw * 32 + hi * 8;

  f32x4 acc[5];
#pragma unroll
  for (int T = 0; T < 5; ++T) acc[T] = (f32x4){0.f, 0.f, 0.f, 0.f};

  float4 xa0, xb0, xa1, xb1;
  bf16x8 af0[5], af1[5];

  // prologue: stage ks = 0
  {
    xa0 = *(const float4*)xch; xb0 = *(const float4*)(xch + 4);
#pragma unroll
    for (int T = 0; T < 5; ++T) af0[T] = *(const bf16x8*)(Arow + T * 16384);
  }
  for (int ks = 0; ks < 32; ks += 2) {
    // prefetch ks+1 into buffer 1
    {
      const float* xr = xch + ((size_t)(ks + 1) << 7);
      xa1 = *(const float4*)xr; xb1 = *(const float4*)(xr + 4);
      const unsigned short* ar = Arow + (ks + 1) * 32;
#pragma unroll
      for (int T = 0; T < 5; ++T) af1[T] = *(const bf16x8*)(ar + T * 16384);
    }
    // compute ks from buffer 0
    {
      bf16x8 bfr;
      ((unsigned*)&bfr)[0] = pack2(xa0.x, xa0.y);
      ((unsigned*)&bfr)[1] = pack2(xa0.z, xa0.w);
      ((unsigned*)&bfr)[2] = pack2(xb0.x, xb0.y);
      ((unsigned*)&bfr)[3] = pack2(xb0.z, xb0.w);
#pragma unroll
      for (int T = 0; T < 5; ++T)
        acc[T] = __builtin_amdgcn_mfma_f32_16x16x32_bf16(af0[T], bfr, acc[T], 0, 0, 0);
    }
    // prefetch ks+2 into buffer 0
    if (ks + 2 < 32) {
      const float* xr = xch + ((size_t)(ks + 2) << 7);
      xa0 = *(const float4*)xr; xb0 = *(const float4*)(xr + 4);
      const unsigned short* ar = Arow + (ks + 2) * 32;
#pragma unroll
      for (int T = 0; T < 5; ++T) af0[T] = *(const bf16x8*)(ar + T * 16384);
    }
    // compute ks+1 from buffer 1
    {
      bf16x8 bfr;
      ((unsigned*)&bfr)[0] = pack2(xa1.x, xa1.y);
      ((unsigned*)&bfr)[1] = pack2(xa1.z, xa1.w);
      ((unsigned*)&bfr)[2] = pack2(xb1.x, xb1.y);
      ((unsigned*)&bfr)[3] = pack2(xb1.z, xb1.w);
#pragma unroll
      for (int T = 0; T < 5; ++T)
        acc[T] = __builtin_amdgcn_mfma_f32_16x16x32_bf16(af1[T], bfr, acc[T], 0, 0, 0);
    }
  }

  // epilogue: write local (pads exact 0), fold bk2 dot via lane-reduce + atomic
  const float wk = wkbq[chw + lo];
#pragma unroll
  for (int T = 0; T < 5; ++T)
#pragma unroll
    for (int r = 0; r < 4; ++r) {
      int cm = T * 16 + hi * 4 + r;
      float av = acc[T][r];
      local_bf[((size_t)inst * CMP_ + cm) * 512 + chw + lo] = f2bf(av);
      float p = av * wk;
      p += __shfl_xor(p, 1); p += __shfl_xor(p, 2);
      p += __shfl_xor(p, 4); p += __shfl_xor(p, 8);
      if (lo == 0 && cm < CM_) atomicAdd(&bk2[inst * CMP_ + cm], p);
    }
}

// ---------------- k3n (MFMA): Wqkt[inst][cm][c] = local@WqWkT^T + bqkadd ----------------
// grid (4, 64)   (reverted to 423-us baseline config to isolate k2 delta)
__global__ __launch_bounds__(256) void k3n_wqkt(
    const unsigned short* __restrict__ local_bf, const unsigned short* __restrict__ WqWkT,
    const float* __restrict__ bqkadd, unsigned short* __restrict__ Wqkt) {
  const int blkc = blockIdx.x, inst = blockIdx.y;
  const int t = threadIdx.x, lane = t & 63, w = t >> 6;
  const int lo = lane & 15, hi = lane >> 4;
  const int cbase = blkc * 128 + w * 32;
  f32x4 acc[5][2];
#pragma unroll
  for (int cT = 0; cT < 2; ++cT) {
    float bv_ = bqkadd[cbase + cT * 16 + lo];
#pragma unroll
    for (int T = 0; T < 5; ++T) acc[T][cT] = (f32x4){bv_, bv_, bv_, bv_};
  }
  const unsigned short* Abase = local_bf + (size_t)inst * 40960;
#pragma unroll 4
  for (int ks = 0; ks < 16; ++ks) {
    const int k = ks * 32 + hi * 8;
    bf16x8 af[5];
#pragma unroll
    for (int T = 0; T < 5; ++T)
      af[T] = *(const bf16x8*)(Abase + (size_t)(T * 16 + lo) * 512 + k);
#pragma unroll
    for (int cT = 0; cT < 2; ++cT) {
      bf16x8 bfr = *(const bf16x8*)(WqWkT + (size_t)(cbase + cT * 16 + lo) * 512 + k);
#pragma unroll
      for (int T = 0; T < 5; ++T)
        acc[T][cT] = __builtin_amdgcn_mfma_f32_16x16x32_bf16(af[T], bfr, acc[T][cT], 0, 0, 0);
    }
  }
#pragma unroll
  for (int T = 0; T < 5; ++T)
#pragma unroll
    for (int cT = 0; cT < 2; ++cT)
#pragma unroll
      for (int r = 0; r < 4; ++r) {
        int cm = T * 16 + hi * 4 + r;
        Wqkt[(size_t)inst * 40960 + (size_t)cm * 512 + cbase + cT * 16 + lo] =
            f2bf(acc[T][cT][r]);
      }
}

// ---------------- kV (MFMA): vWt[c2][cm] = WvWcT@g^T + bvWc ----------------
// grid (8, 2)
__global__ __launch_bounds__(256) void kV_vwt(
    const unsigned short* __restrict__ WvWcT, const float* __restrict__ g,
    const float* __restrict__ bv, const float* __restrict__ Wc,
    unsigned short* __restrict__ vWt) {
  const int blk = blockIdx.x, half = blockIdx.y;
  const int t = threadIdx.x, lane = t & 63, w = t >> 6;
  const int lo = lane & 15, hi = lane >> 4;
  __shared__ float bvp[4][64];
  __shared__ float bvs[64];
  {
    int c2l = t & 63, part = t >> 6;
    float s = 0.f;
    for (int m = part * 64; m < part * 64 + 64; ++m)
      s += bv[m] * Wc[(size_t)m * 512 + blk * 64 + c2l];
    bvp[part][c2l] = s;
  }
  __syncthreads();
  if (t < 64) bvs[t] = bvp[0][t] + bvp[1][t] + bvp[2][t] + bvp[3][t];
  __syncthreads();
  const int r2 = blk * 64 + w * 16;
  f32x4 acc[3];
#pragma unroll
  for (int j = 0; j < 3; ++j) acc[j] = (f32x4){0.f, 0.f, 0.f, 0.f};
#pragma unroll 4
  for (int ks = 0; ks < 16; ++ks) {
    const int k = ks * 32 + hi * 8;
    bf16x8 afr = *(const bf16x8*)(WvWcT + (size_t)(r2 + lo) * 512 + k);
#pragma unroll
    for (int j = 0; j < 3; ++j) {
      int cm = (half * 3 + j) * 16 + lo;
      cm = cm > 75 ? 75 : cm;
      const float* gr = g + (size_t)cm * 512 + k;
      float4 v0 = *(const float4*)gr, v1 = *(const float4*)(gr + 4);
      bf16x8 bfr;
      ((unsigned*)&bfr)[0] = pack2(v0.x, v0.y);
      ((unsigned*)&bfr)[1] = pack2(v0.z, v0.w);
      ((unsigned*)&bfr)[2] = pack2(v1.x, v1.y);
      ((unsigned*)&bfr)[3] = pack2(v1.z, v1.w);
      acc[j] = __builtin_amdgcn_mfma_f32_16x16x32_bf16(afr, bfr, acc[j], 0, 0, 0);
    }
  }
#pragma unroll
  for (int j = 0; j < 3; ++j)
#pragma unroll
    for (int rr = 0; rr < 4; ++rr) {
      int c2g = blk * 64 + w * 16 + hi * 4 + rr;
      vWt[(size_t)c2g * 96 + (half * 3 + j) * 16 + lo] =
          f2bf(acc[j][rr] + bvs[w * 16 + hi * 4 + rr]);
    }
}

// ---------------- K4 (MFMA): logits -> in-register softmax -> y (BN+ReLU) ----------------
// grid (8, 64)
__global__ __launch_bounds__(256) void k4_attn(
    const float* __restrict__ x, const unsigned short* __restrict__ Wqkt,
    const float* __restrict__ bk2, const unsigned short* __restrict__ vWt,
    const float* __restrict__ inv_arr, const float* __restrict__ add_arr,
    float* __restrict__ y) {
  const int pt = blockIdx.x, inst = blockIdx.y;
  const int b = inst >> 4, n = inst & 15, bh = n >> 2, bw = n & 3;
  __shared__ unsigned short Xs[4][32 * 72];
  __shared__ unsigned short Att[4][32 * 96];
  __shared__ float bn_s[1024];
  const int t = threadIdx.x, lane = t & 63, w = t >> 6;
  const int lo = lane & 15, hi = lane >> 4;
  const int pq = lane & 7, chp0 = lane >> 3;

  for (int i = t; i < 512; i += 256) { bn_s[i] = inv_arr[i]; bn_s[512 + i] = add_arr[i]; }

  const int imgrow = bh * 32 + pt * 4 + w;
  const size_t pixbase = (size_t)imgrow * 128 + bw * 32;
  const size_t xrowbase = (((size_t)b * 512) << 14) + pixbase;
  const unsigned short* Wi = Wqkt + (size_t)inst * 40960;

  f32x4 acc[2][5];
#pragma unroll
  for (int T = 0; T < 5; ++T) {
    f32x4 bv;
#pragma unroll
    for (int r = 0; r < 4; ++r) bv[r] = bk2[inst * CMP_ + T * 16 + hi * 4 + r];
    acc[0][T] = bv; acc[1][T] = bv;
  }

  for (int kc = 0; kc < 8; ++kc) {
#pragma unroll
    for (int i = 0; i < 4; ++i) {
      int chp = chp0 + i * 8;
      int ch = kc * 64 + chp * 2;
      const float* xa = x + xrowbase + ((size_t)ch << 14) + pq * 4;
      float4 va = *(const float4*)(xa);
      float4 vb = *(const float4*)(xa + 16384);
      unsigned short* dst = &Xs[w][(pq * 4) * 72 + chp * 2];
      *(unsigned*)(dst + 0 * 72) = pack2(va.x, vb.x);
      *(unsigned*)(dst + 1 * 72) = pack2(va.y, vb.y);
      *(unsigned*)(dst + 2 * 72) = pack2(va.z, vb.z);
      *(unsigned*)(dst + 3 * 72) = pack2(va.w, vb.w);
    }
#pragma unroll
    for (int ks = 0; ks < 2; ++ks) {
      int kb = kc * 64 + ks * 32 + hi * 8;
      bf16x8 b0 = *(bf16x8*)(&Xs[w][lo * 72 + ks * 32 + hi * 8]);
      bf16x8 b1 = *(bf16x8*)(&Xs[w][(16 + lo) * 72 + ks * 32 + hi * 8]);
#pragma unroll
      for (int T = 0; T < 5; ++T) {
        bf16x8 afr = *(const bf16x8*)(Wi + (size_t)(T * 16 + lo) * 512 + kb);
        acc[0][T] = __builtin_amdgcn_mfma_f32_16x16x32_bf16(afr, b0, acc[0][T], 0, 0, 0);
        acc[1][T] = __builtin_amdgcn_mfma_f32_16x16x32_bf16(afr, b1, acc[1][T], 0, 0, 0);
      }
    }
  }

#pragma unroll
  for (int p = 0; p < 2; ++p) {
    float m = -1e30f;
#pragma unroll
    for (int T = 0; T < 5; ++T)
#pragma unroll
      for (int r = 0; r < 4; ++r) m = fmaxf(m, acc[p][T][r]);
    m = fmaxf(m, __shfl_xor(m, 16));
    m = fmaxf(m, __shfl_xor(m, 32));
    float e[5][4];
    float s = 0.f;
#pragma unroll
    for (int T = 0; T < 5; ++T)
#pragma unroll
      for (int r = 0; r < 4; ++r) { float ev = __expf(acc[p][T][r] - m); e[T][r] = ev; s += ev; }
    s += __shfl_xor(s, 16);
    s += __shfl_xor(s, 32);
    float rinv = 1.f / s;
    int px = p * 16 + lo;
#pragma unroll
    for (int T = 0; T < 5; ++T) {
      unsigned l32 = pack2(e[T][0] * rinv, e[T][1] * rinv);
      unsigned h32 = pack2(e[T][2] * rinv, e[T][3] * rinv);
      *(unsigned long long*)(&Att[w][px * 96 + T * 16 + hi * 4]) =
          (unsigned long long)l32 | ((unsigned long long)h32 << 32);
    }
    *(unsigned long long*)(&Att[w][px * 96 + 80 + hi * 4]) = 0ull;
  }

  __syncthreads();

  bf16x8 bfr3[2][3];
#pragma unroll
  for (int p = 0; p < 2; ++p)
#pragma unroll
    for (int ks = 0; ks < 3; ++ks)
      bfr3[p][ks] = *(bf16x8*)(&Att[w][(p * 16 + lo) * 96 + ks * 32 + hi * 8]);

  for (int cT = 0; cT < 32; ++cT) {
    f32x4 a0 = (f32x4){0.f, 0.f, 0.f, 0.f}, a1 = a0;
    const unsigned short* vr = vWt + (size_t)(cT * 16 + lo) * 96;
#pragma unroll
    for (int ks = 0; ks < 3; ++ks) {
      bf16x8 afr = *(const bf16x8*)(vr + ks * 32 + hi * 8);
      a0 = __builtin_amdgcn_mfma_f32_16x16x32_bf16(afr, bfr3[0][ks], a0, 0, 0, 0);
      a1 = __builtin_amdgcn_mfma_f32_16x16x32_bf16(afr, bfr3[1][ks], a1, 0, 0, 0);
    }
    f32x4 inv4 = *(f32x4*)(&bn_s[cT * 16 + hi * 4]);
    f32x4 add4 = *(f32x4*)(&bn_s[512 + cT * 16 + hi * 4]);
#pragma unroll
    for (int r = 0; r < 4; ++r) {
      int ch = cT * 16 + hi * 4 + r;
      float v0 = fmaxf(a0[r] * inv4[r] + add4[r], 0.f);
      float v1 = fmaxf(a1[r] * inv4[r] + add4[r], 0.f);
      size_t yb = (((size_t)(b * 512 + ch)) << 14) + pixbase;
      y[yb + lo] = v0;
      y[yb + 16 + lo] = v1;
    }
  }
}

// ---------------- host launch ----------------
extern "C" void kernel_launch(void* const* d_in, const int* in_sizes, int n_in,
                              void* d_out, int out_size, void* d_ws, size_t ws_size,
                              hipStream_t stream) {
  (void)in_sizes; (void)n_in; (void)out_size; (void)ws_size;
  const float* x     = (const float*)d_in[0];
  const float* sim   = (const float*)d_in[1];
  const float* g     = (const float*)d_in[2];
  const float* Wq    = (const float*)d_in[3];
  const float* bq    = (const float*)d_in[4];
  const float* Wk    = (const float*)d_in[5];
  const float* bk    = (const float*)d_in[6];
  const float* Wv    = (const float*)d_in[7];
  const float* bv    = (const float*)d_in[8];
  const float* Wc    = (const float*)d_in[9];
  const float* gamma = (const float*)d_in[10];
  const float* beta  = (const float*)d_in[11];
  const float* mean  = (const float*)d_in[12];
  const float* var   = (const float*)d_in[13];
  float* out = (float*)d_out;
  float* ws  = (float*)d_ws;
  float* y   = out;                    // [4][512][128][128]
  float* pcs = out + 33554432;         // [4][76][4][4]
  unsigned short* expsim  = (unsigned short*)(ws + OFF_EXPSIM);
  unsigned short* localbf = (unsigned short*)(ws + OFF_LOCALBF);
  unsigned short* Wqkt    = (unsigned short*)(ws + OFF_WQKT);
  unsigned short* vWt     = (unsigned short*)(ws + OFF_VWT);
  unsigned short* WqWkT   = (unsigned short*)(ws + OFF_WQWKT);
  unsigned short* WvWcT   = (unsigned short*)(ws + OFF_WVWCT);

  hipLaunchKernelGGL(kW_pre, dim3(65, 2), dim3(256), 0, stream,
                     Wq, Wk, Wv, Wc, bq, bk, gamma, beta, mean, var,
                     WqWkT, WvWcT, ws + OFF_WKBQ, ws + OFF_BQKADD,
                     ws + OFF_INV, ws + OFF_ADD, ws + OFF_CBB);
  hipLaunchKernelGGL(k1_stats, dim3(CMP_, 64), dim3(256), 0, stream,
                     sim, pcs, ws + OFF_CBB, expsim, ws + OFF_BK2);
  hipLaunchKernelGGL(k2_local, dim3(4, 64), dim3(512), 0, stream,
                     x, expsim, ws + OFF_WKBQ, localbf, ws + OFF_BK2);
  hipLaunchKernelGGL(k3n_wqkt, dim3(4, 64), dim3(256), 0, stream,
                     localbf, WqWkT, ws + OFF_BQKADD, Wqkt);
  hipLaunchKernelGGL(kV_vwt, dim3(8, 2), dim3(256), 0, stream,
                     WvWcT, g, bv, Wc, vWt);
  hipLaunchKernelGGL(k4_attn, dim3(8, 64), dim3(256), 0, stream,
                     x, Wqkt, ws + OFF_BK2, vWt,
                     ws + OFF_INV, ws + OFF_ADD, y);
}

// Round 3
// 404.676 us; speedup vs baseline: 1.1401x; 1.0675x over previous
//
#include <hip/hip_runtime.h>

// ---------------- problem constants ----------------
// b=4, C=512, h=w=128, BH=BW=4 -> 64 instances, P=1024 pixels each
// CM=76 (pad 80/96), mid=256
#define CM_    76
#define CMP_   80

typedef __attribute__((ext_vector_type(4))) float f32x4;
typedef __attribute__((ext_vector_type(8))) short bf16x8;

__device__ __forceinline__ unsigned short f2bf(float f) {
  union { float f; unsigned u; } v; v.f = f;
  unsigned r = v.u + 0x7FFFu + ((v.u >> 16) & 1u);
  return (unsigned short)(r >> 16);
}
__device__ __forceinline__ unsigned pack2(float a, float b) {
  return (unsigned)f2bf(a) | ((unsigned)f2bf(b) << 16);
}

// async global->LDS DMA, 16B per lane, linear LDS dest (wave-uniform base + lane*16)
#define GLOAD_LDS16(gsrc, ldst)                                                      \
  __builtin_amdgcn_global_load_lds(                                                  \
      (const __attribute__((address_space(1))) void*)(gsrc),                         \
      (__attribute__((address_space(3))) void*)(ldst), 16, 0, 0)

// ---------------- workspace layout (float offsets; all 16B-aligned) ----------------
#define OFF_BK2     0            // [64][80] f32 (init cbb / -1e30 pads, k2 atomics add)
#define OFF_INV     5120         // [512] f32
#define OFF_ADD     5632         // [512] f32
#define OFF_WKBQ    6144         // [512] f32  (Wk@bq)
#define OFF_BQKADD  6656         // [512] f32  (Wq@bk)
#define OFF_CBB     7168         // [1] f32 (pad to 7172)
#define OFF_EXPSIM  7172         // bf16 [64][80][1024]  (2,621,440 f)
#define OFF_LOCALBF 2628612      // bf16 [64][80][512]   (1,310,720 f)
#define OFF_WQKT    3939332      // bf16 [64][80][512]
#define OFF_VWT     5250052      // bf16 [512][96]
#define OFF_WQWKT   5274628      // bf16 [512][512] (Wq@Wk^T)
#define OFF_WVWCT   5405700      // bf16 [512][512] (Wc^T@Wv^T)
// total 5,536,772 floats = 22.1 MB

// ---------------- kW (one-off): WqWkT / WvWcT + (blk.x==64) scalar pre ----------------
// grid (65, 2)
__global__ __launch_bounds__(256) void kW_pre(
    const float* __restrict__ Wq, const float* __restrict__ Wk,
    const float* __restrict__ Wv, const float* __restrict__ Wc,
    const float* __restrict__ bq, const float* __restrict__ bk,
    const float* __restrict__ gamma, const float* __restrict__ beta,
    const float* __restrict__ mean, const float* __restrict__ var,
    unsigned short* __restrict__ WqWkT, unsigned short* __restrict__ WvWcT,
    float* __restrict__ wkbq, float* __restrict__ bqkadd,
    float* __restrict__ invp, float* __restrict__ addp, float* __restrict__ cbbp) {
  const int sel = blockIdx.y;
  if (blockIdx.x == 64) {       // scalar pre-kernel half (c = sel*256 + t)
    const int c = sel * 256 + threadIdx.x;
    const float* wkr = Wk + (size_t)c * 256;
    const float* wqr = Wq + (size_t)c * 256;
    float s1 = 0.f, s2 = 0.f;
    for (int m = 0; m < 256; ++m) { s1 += wkr[m] * bq[m]; s2 += wqr[m] * bk[m]; }
    wkbq[c] = s1; bqkadd[c] = s2;
    float iv = gamma[c] * rsqrtf(var[c] + 1e-5f);
    invp[c] = iv; addp[c] = beta[c] - mean[c] * iv;
    if (c == 0) {
      float s = 0.f;
      for (int m = 0; m < 256; ++m) s += bq[m] * bk[m];
      cbbp[0] = s;
    }
    return;
  }
  const int r0 = (blockIdx.x >> 3) * 64, c0 = (blockIdx.x & 7) * 64;
  __shared__ __align__(16) unsigned short Asm[64 * 40];
  __shared__ __align__(16) unsigned short Bsm[64 * 40];
  const int t = threadIdx.x, lane = t & 63, w = t >> 6;
  const int lo = lane & 15, hi = lane >> 4;
  f32x4 acc[4];
#pragma unroll
  for (int cT = 0; cT < 4; ++cT) acc[cT] = (f32x4){0.f, 0.f, 0.f, 0.f};
  const float* Bsrc = sel ? Wv : Wk;
  for (int kc = 0; kc < 8; ++kc) {
    const int k0 = kc * 32;
    __syncthreads();
    {
      int nn = t >> 2, mq = (t & 3) * 8;
      const float* src = Bsrc + (size_t)(c0 + nn) * 256 + k0 + mq;
      float4 v0 = *(const float4*)src, v1 = *(const float4*)(src + 4);
      unsigned* d = (unsigned*)&Bsm[nn * 40 + mq];
      d[0] = pack2(v0.x, v0.y); d[1] = pack2(v0.z, v0.w);
      d[2] = pack2(v1.x, v1.y); d[3] = pack2(v1.z, v1.w);
    }
    if (sel == 0) {
      int r = t >> 2, mq = (t & 3) * 8;
      const float* src = Wq + (size_t)(r0 + r) * 256 + k0 + mq;
      float4 v0 = *(const float4*)src, v1 = *(const float4*)(src + 4);
      unsigned* d = (unsigned*)&Asm[r * 40 + mq];
      d[0] = pack2(v0.x, v0.y); d[1] = pack2(v0.z, v0.w);
      d[2] = pack2(v1.x, v1.y); d[3] = pack2(v1.z, v1.w);
    } else {
      int m = t >> 3, c2q = (t & 7) * 8;
      const float* src = Wc + (size_t)(k0 + m) * 512 + r0 + c2q;
      float4 v0 = *(const float4*)src, v1 = *(const float4*)(src + 4);
      Asm[(c2q + 0) * 40 + m] = f2bf(v0.x); Asm[(c2q + 1) * 40 + m] = f2bf(v0.y);
      Asm[(c2q + 2) * 40 + m] = f2bf(v0.z); Asm[(c2q + 3) * 40 + m] = f2bf(v0.w);
      Asm[(c2q + 4) * 40 + m] = f2bf(v1.x); Asm[(c2q + 5) * 40 + m] = f2bf(v1.y);
      Asm[(c2q + 6) * 40 + m] = f2bf(v1.z); Asm[(c2q + 7) * 40 + m] = f2bf(v1.w);
    }
    __syncthreads();
    bf16x8 afr = *(bf16x8*)(&Asm[(w * 16 + lo) * 40 + hi * 8]);
#pragma unroll
    for (int cT = 0; cT < 4; ++cT) {
      bf16x8 bfr = *(bf16x8*)(&Bsm[(cT * 16 + lo) * 40 + hi * 8]);
      acc[cT] = __builtin_amdgcn_mfma_f32_16x16x32_bf16(afr, bfr, acc[cT], 0, 0, 0);
    }
  }
  unsigned short* dst = sel ? WvWcT : WqWkT;
#pragma unroll
  for (int cT = 0; cT < 4; ++cT)
#pragma unroll
    for (int rr = 0; rr < 4; ++rr)
      dst[(size_t)(r0 + w * 16 + hi * 4 + rr) * 512 + c0 + cT * 16 + lo] = f2bf(acc[cT][rr]);
}

// ---------------- K1: stats + materialize expsim bf16 (scaled), init bk2 ----------------
// grid (80, 64), block 256
__global__ __launch_bounds__(256) void k1_stats(
    const float* __restrict__ sim, float* __restrict__ pcs,
    const float* __restrict__ cbbp,
    unsigned short* __restrict__ expsim, float* __restrict__ bk2) {
  const int cm = blockIdx.x, inst = blockIdx.y;
  const int t = threadIdx.x;
  unsigned short* erow = expsim + (size_t)inst * 81920 + (size_t)cm * 1024;
  if (cm >= CM_) {                          // pad rows: zero, bk2 = -inf
    ((unsigned long long*)erow)[t] = 0ull;
    if (t == 0) bk2[inst * CMP_ + cm] = -1e30f;
    return;
  }
  const int b = inst >> 4, n = inst & 15, bh = n >> 2, bw = n & 3;
  const float* base = sim + ((size_t)(b * CM_ + cm) << 14);
  float v[4];
  float lsum = 0.f, lmax = -1e30f;
#pragma unroll
  for (int i = 0; i < 4; ++i) {
    int p = t + (i << 8);
    int pix = ((bh * 32 + (p >> 5)) << 7) + bw * 32 + (p & 31);
    float xv = base[pix];
    v[i] = xv; lsum += xv; lmax = fmaxf(lmax, xv);
  }
#pragma unroll
  for (int off = 32; off; off >>= 1) {
    lsum += __shfl_down(lsum, off);
    lmax = fmaxf(lmax, __shfl_down(lmax, off));
  }
  __shared__ float ssum[4], smax[4], bc[2];
  const int wid = t >> 6;
  if ((t & 63) == 0) { ssum[wid] = lsum; smax[wid] = lmax; }
  __syncthreads();
  if (t == 0) {
    bc[0] = ssum[0] + ssum[1] + ssum[2] + ssum[3];
    bc[1] = fmaxf(fmaxf(smax[0], smax[1]), fmaxf(smax[2], smax[3]));
  }
  __syncthreads();
  const float M = bc[1];
  float le = 0.f;
#pragma unroll
  for (int i = 0; i < 4; ++i) le += __expf(v[i] - M);
#pragma unroll
  for (int off = 32; off; off >>= 1) le += __shfl_down(le, off);
  if ((t & 63) == 0) ssum[wid] = le;
  __syncthreads();
  if (t == 0) {
    float E = ssum[0] + ssum[1] + ssum[2] + ssum[3];
    float conf = bc[0] * (1.f / 1024.f);
    pcs[((b * CM_ + cm) << 4) + n] = conf;
    bk2[inst * CMP_ + cm] = cbbp[0];        // base for k2's atomic accumulation
    bc[0] = conf / E;                        // broadcast scale
  }
  __syncthreads();
  const float sc = bc[0];
#pragma unroll
  for (int i = 0; i < 4; ++i) {
    int p = t + (i << 8);
    erow[p] = f2bf(sc * __expf(v[i] - M));
  }
}

// ---------------- K2 v5 (global_load_lds + 2-phase LDS dbuf): local = expsim @ x^T ----------------
// History: v1/v3 register-destined loads get SERIALIZED by regalloc (VGPR 44-48, ~7.2K cyc/step
//   = 7 loads x ~1000cyc latency each) -> stuck at 1.2-1.4 TB/s regardless of occupancy.
// v5: async DMA staging (no dest VGPRs -> whole 21KB tile in flight), 2-phase double buffer,
//   XOR-swizzled LDS (source-pre-swizzle, linear DMA dest; read with same involution).
// grid (4, 64), block 512 = 8 waves x 16 ch. Per K-step (32 px): A 80x32 bf16 (5 instrs),
//   B 128ch x 32px f32 (16 instrs). Traffic ~181 MB -> HBM-bound ~30-45 us.
__global__ __launch_bounds__(512) void k2_local(
    const float* __restrict__ x, const unsigned short* __restrict__ expsim,
    const float* __restrict__ wkbq,
    unsigned short* __restrict__ local_bf, float* __restrict__ bk2) {
  const int cc = blockIdx.x, inst = blockIdx.y;
  const int b = inst >> 4, n = inst & 15, bh = n >> 2, bw = n & 3;
  const int t = threadIdx.x, lane = t & 63, w = t >> 6;
  const int lo = lane & 15, hi = lane >> 4;
  const int chw = cc * 128 + w * 16;

  // LDS: A[80 rows][32px bf16 = 64B], B[128 ch][32px f32 = 128B], double-buffered = 42 KB
  __shared__ __align__(16) unsigned char AsB[2][80 * 64];
  __shared__ __align__(16) unsigned char BsB[2][128 * 128];

  // ---- staging source pointers (pre-swizzled global addresses; LDS dest stays linear) ----
  // B instr j (j=0,1): 1KB = 8 ch-rows x 128B. lane: ch_local = w*16+j*8+(lane>>3),
  //   physical 16B-slot p = lane&7 receives logical slot p ^ (ch&7)  (ch&7 == lane>>3).
  const int bq_ = ((lane & 7) ^ (lane >> 3)) * 4;     // swizzled px*4 within 32-px row
  const float* pB0 = x + (((size_t)(b * 512 + cc * 128 + w * 16 + 0 + (lane >> 3))) << 14)
                       + (size_t)(bh * 32) * 128 + bw * 32 + bq_;
  const float* pB1 = x + (((size_t)(b * 512 + cc * 128 + w * 16 + 8 + (lane >> 3))) << 14)
                       + (size_t)(bh * 32) * 128 + bw * 32 + bq_;
  // A instr (waves 0..4): 1KB = 16 cm-rows x 64B. lane: row = w*16+(lane>>2),
  //   physical slot p = lane&3 receives logical slot p ^ (row&3)  (row&3 == (lane>>2)&3).
  const unsigned short* pA = expsim + (size_t)inst * 81920
                           + (size_t)(w * 16 + (lane >> 2)) * 1024
                           + ((lane & 3) ^ ((lane >> 2) & 3)) * 8;

  // ---- compute-side constant offsets (same involutions) ----
  const int brow = (w * 16 + lo) * 128;
  const int bs0 = (((hi << 1) | 0) ^ (lo & 7)) << 4;
  const int bs1 = (((hi << 1) | 1) ^ (lo & 7)) << 4;
  const int aoff = (hi ^ (lo & 3)) << 4;

  f32x4 acc[5];
#pragma unroll
  for (int T = 0; T < 5; ++T) acc[T] = (f32x4){0.f, 0.f, 0.f, 0.f};

  // prologue: stage t=0 into buf 0
  GLOAD_LDS16(pB0, &BsB[0][(w * 16 + 0) * 128]);
  GLOAD_LDS16(pB1, &BsB[0][(w * 16 + 8) * 128]);
  if (w < 5) GLOAD_LDS16(pA, &AsB[0][w * 1024]);
  pB0 += 128; pB1 += 128; pA += 32;
  __syncthreads();   // drains vmcnt(0): t=0 tile resident

  for (int tt = 0; tt < 32; ++tt) {
    const int cur = tt & 1;
    if (tt < 31) {   // stage t+1 into the other buffer (in flight during compute)
      const int nxt = cur ^ 1;
      GLOAD_LDS16(pB0, &BsB[nxt][(w * 16 + 0) * 128]);
      GLOAD_LDS16(pB1, &BsB[nxt][(w * 16 + 8) * 128]);
      if (w < 5) GLOAD_LDS16(pA, &AsB[nxt][w * 1024]);
      pB0 += 128; pB1 += 128; pA += 32;
    }
    // compute step tt from buf[cur]
    {
      const unsigned char* BsP = BsB[cur];
      const unsigned char* AsP = AsB[cur];
      float4 v0 = *(const float4*)(BsP + brow + bs0);
      float4 v1 = *(const float4*)(BsP + brow + bs1);
      bf16x8 bfr;
      ((unsigned*)&bfr)[0] = pack2(v0.x, v0.y);
      ((unsigned*)&bfr)[1] = pack2(v0.z, v0.w);
      ((unsigned*)&bfr)[2] = pack2(v1.x, v1.y);
      ((unsigned*)&bfr)[3] = pack2(v1.z, v1.w);
#pragma unroll
      for (int T = 0; T < 5; ++T) {
        bf16x8 afr = *(const bf16x8*)(AsP + ((T * 16 + lo) << 6) + aoff);
        acc[T] = __builtin_amdgcn_mfma_f32_16x16x32_bf16(afr, bfr, acc[T], 0, 0, 0);
      }
    }
    __syncthreads();  // waits vmcnt(0) (stage t+1 arrived) + all waves done reading buf[cur]
  }

  // epilogue: write local (pads exact 0), fold bk2 dot via lane-reduce + atomic
  const float wk = wkbq[chw + lo];
#pragma unroll
  for (int T = 0; T < 5; ++T)
#pragma unroll
    for (int r = 0; r < 4; ++r) {
      int cm = T * 16 + hi * 4 + r;
      float av = acc[T][r];
      local_bf[((size_t)inst * CMP_ + cm) * 512 + chw + lo] = f2bf(av);
      float p = av * wk;
      p += __shfl_xor(p, 1); p += __shfl_xor(p, 2);
      p += __shfl_xor(p, 4); p += __shfl_xor(p, 8);
      if (lo == 0 && cm < CM_) atomicAdd(&bk2[inst * CMP_ + cm], p);
    }
}

// ---------------- k3n (MFMA): Wqkt[inst][cm][c] = local@WqWkT^T + bqkadd ----------------
// grid (4, 64)
__global__ __launch_bounds__(256) void k3n_wqkt(
    const unsigned short* __restrict__ local_bf, const unsigned short* __restrict__ WqWkT,
    const float* __restrict__ bqkadd, unsigned short* __restrict__ Wqkt) {
  const int blkc = blockIdx.x, inst = blockIdx.y;
  const int t = threadIdx.x, lane = t & 63, w = t >> 6;
  const int lo = lane & 15, hi = lane >> 4;
  const int cbase = blkc * 128 + w * 32;
  f32x4 acc[5][2];
#pragma unroll
  for (int cT = 0; cT < 2; ++cT) {
    float bv_ = bqkadd[cbase + cT * 16 + lo];
#pragma unroll
    for (int T = 0; T < 5; ++T) acc[T][cT] = (f32x4){bv_, bv_, bv_, bv_};
  }
  const unsigned short* Abase = local_bf + (size_t)inst * 40960;
#pragma unroll 4
  for (int ks = 0; ks < 16; ++ks) {
    const int k = ks * 32 + hi * 8;
    bf16x8 af[5];
#pragma unroll
    for (int T = 0; T < 5; ++T)
      af[T] = *(const bf16x8*)(Abase + (size_t)(T * 16 + lo) * 512 + k);
#pragma unroll
    for (int cT = 0; cT < 2; ++cT) {
      bf16x8 bfr = *(const bf16x8*)(WqWkT + (size_t)(cbase + cT * 16 + lo) * 512 + k);
#pragma unroll
      for (int T = 0; T < 5; ++T)
        acc[T][cT] = __builtin_amdgcn_mfma_f32_16x16x32_bf16(af[T], bfr, acc[T][cT], 0, 0, 0);
    }
  }
#pragma unroll
  for (int T = 0; T < 5; ++T)
#pragma unroll
    for (int cT = 0; cT < 2; ++cT)
#pragma unroll
      for (int r = 0; r < 4; ++r) {
        int cm = T * 16 + hi * 4 + r;
        Wqkt[(size_t)inst * 40960 + (size_t)cm * 512 + cbase + cT * 16 + lo] =
            f2bf(acc[T][cT][r]);
      }
}

// ---------------- kV (MFMA): vWt[c2][cm] = WvWcT@g^T + bvWc ----------------
// grid (8, 2)
__global__ __launch_bounds__(256) void kV_vwt(
    const unsigned short* __restrict__ WvWcT, const float* __restrict__ g,
    const float* __restrict__ bv, const float* __restrict__ Wc,
    unsigned short* __restrict__ vWt) {
  const int blk = blockIdx.x, half = blockIdx.y;
  const int t = threadIdx.x, lane = t & 63, w = t >> 6;
  const int lo = lane & 15, hi = lane >> 4;
  __shared__ float bvp[4][64];
  __shared__ float bvs[64];
  {
    int c2l = t & 63, part = t >> 6;
    float s = 0.f;
    for (int m = part * 64; m < part * 64 + 64; ++m)
      s += bv[m] * Wc[(size_t)m * 512 + blk * 64 + c2l];
    bvp[part][c2l] = s;
  }
  __syncthreads();
  if (t < 64) bvs[t] = bvp[0][t] + bvp[1][t] + bvp[2][t] + bvp[3][t];
  __syncthreads();
  const int r2 = blk * 64 + w * 16;
  f32x4 acc[3];
#pragma unroll
  for (int j = 0; j < 3; ++j) acc[j] = (f32x4){0.f, 0.f, 0.f, 0.f};
#pragma unroll 4
  for (int ks = 0; ks < 16; ++ks) {
    const int k = ks * 32 + hi * 8;
    bf16x8 afr = *(const bf16x8*)(WvWcT + (size_t)(r2 + lo) * 512 + k);
#pragma unroll
    for (int j = 0; j < 3; ++j) {
      int cm = (half * 3 + j) * 16 + lo;
      cm = cm > 75 ? 75 : cm;
      const float* gr = g + (size_t)cm * 512 + k;
      float4 v0 = *(const float4*)gr, v1 = *(const float4*)(gr + 4);
      bf16x8 bfr;
      ((unsigned*)&bfr)[0] = pack2(v0.x, v0.y);
      ((unsigned*)&bfr)[1] = pack2(v0.z, v0.w);
      ((unsigned*)&bfr)[2] = pack2(v1.x, v1.y);
      ((unsigned*)&bfr)[3] = pack2(v1.z, v1.w);
      acc[j] = __builtin_amdgcn_mfma_f32_16x16x32_bf16(afr, bfr, acc[j], 0, 0, 0);
    }
  }
#pragma unroll
  for (int j = 0; j < 3; ++j)
#pragma unroll
    for (int rr = 0; rr < 4; ++rr) {
      int c2g = blk * 64 + w * 16 + hi * 4 + rr;
      vWt[(size_t)c2g * 96 + (half * 3 + j) * 16 + lo] =
          f2bf(acc[j][rr] + bvs[w * 16 + hi * 4 + rr]);
    }
}

// ---------------- K4 (MFMA): logits -> in-register softmax -> y (BN+ReLU) ----------------
// grid (8, 64)
__global__ __launch_bounds__(256) void k4_attn(
    const float* __restrict__ x, const unsigned short* __restrict__ Wqkt,
    const float* __restrict__ bk2, const unsigned short* __restrict__ vWt,
    const float* __restrict__ inv_arr, const float* __restrict__ add_arr,
    float* __restrict__ y) {
  const int pt = blockIdx.x, inst = blockIdx.y;
  const int b = inst >> 4, n = inst & 15, bh = n >> 2, bw = n & 3;
  __shared__ unsigned short Xs[4][32 * 72];
  __shared__ unsigned short Att[4][32 * 96];
  __shared__ float bn_s[1024];
  const int t = threadIdx.x, lane = t & 63, w = t >> 6;
  const int lo = lane & 15, hi = lane >> 4;
  const int pq = lane & 7, chp0 = lane >> 3;

  for (int i = t; i < 512; i += 256) { bn_s[i] = inv_arr[i]; bn_s[512 + i] = add_arr[i]; }

  const int imgrow = bh * 32 + pt * 4 + w;
  const size_t pixbase = (size_t)imgrow * 128 + bw * 32;
  const size_t xrowbase = (((size_t)b * 512) << 14) + pixbase;
  const unsigned short* Wi = Wqkt + (size_t)inst * 40960;

  f32x4 acc[2][5];
#pragma unroll
  for (int T = 0; T < 5; ++T) {
    f32x4 bv;
#pragma unroll
    for (int r = 0; r < 4; ++r) bv[r] = bk2[inst * CMP_ + T * 16 + hi * 4 + r];
    acc[0][T] = bv; acc[1][T] = bv;
  }

  for (int kc = 0; kc < 8; ++kc) {
#pragma unroll
    for (int i = 0; i < 4; ++i) {
      int chp = chp0 + i * 8;
      int ch = kc * 64 + chp * 2;
      const float* xa = x + xrowbase + ((size_t)ch << 14) + pq * 4;
      float4 va = *(const float4*)(xa);
      float4 vb = *(const float4*)(xa + 16384);
      unsigned short* dst = &Xs[w][(pq * 4) * 72 + chp * 2];
      *(unsigned*)(dst + 0 * 72) = pack2(va.x, vb.x);
      *(unsigned*)(dst + 1 * 72) = pack2(va.y, vb.y);
      *(unsigned*)(dst + 2 * 72) = pack2(va.z, vb.z);
      *(unsigned*)(dst + 3 * 72) = pack2(va.w, vb.w);
    }
#pragma unroll
    for (int ks = 0; ks < 2; ++ks) {
      int kb = kc * 64 + ks * 32 + hi * 8;
      bf16x8 b0 = *(bf16x8*)(&Xs[w][lo * 72 + ks * 32 + hi * 8]);
      bf16x8 b1 = *(bf16x8*)(&Xs[w][(16 + lo) * 72 + ks * 32 + hi * 8]);
#pragma unroll
      for (int T = 0; T < 5; ++T) {
        bf16x8 afr = *(const bf16x8*)(Wi + (size_t)(T * 16 + lo) * 512 + kb);
        acc[0][T] = __builtin_amdgcn_mfma_f32_16x16x32_bf16(afr, b0, acc[0][T], 0, 0, 0);
        acc[1][T] = __builtin_amdgcn_mfma_f32_16x16x32_bf16(afr, b1, acc[1][T], 0, 0, 0);
      }
    }
  }

#pragma unroll
  for (int p = 0; p < 2; ++p) {
    float m = -1e30f;
#pragma unroll
    for (int T = 0; T < 5; ++T)
#pragma unroll
      for (int r = 0; r < 4; ++r) m = fmaxf(m, acc[p][T][r]);
    m = fmaxf(m, __shfl_xor(m, 16));
    m = fmaxf(m, __shfl_xor(m, 32));
    float e[5][4];
    float s = 0.f;
#pragma unroll
    for (int T = 0; T < 5; ++T)
#pragma unroll
      for (int r = 0; r < 4; ++r) { float ev = __expf(acc[p][T][r] - m); e[T][r] = ev; s += ev; }
    s += __shfl_xor(s, 16);
    s += __shfl_xor(s, 32);
    float rinv = 1.f / s;
    int px = p * 16 + lo;
#pragma unroll
    for (int T = 0; T < 5; ++T) {
      unsigned l32 = pack2(e[T][0] * rinv, e[T][1] * rinv);
      unsigned h32 = pack2(e[T][2] * rinv, e[T][3] * rinv);
      *(unsigned long long*)(&Att[w][px * 96 + T * 16 + hi * 4]) =
          (unsigned long long)l32 | ((unsigned long long)h32 << 32);
    }
    *(unsigned long long*)(&Att[w][px * 96 + 80 + hi * 4]) = 0ull;
  }

  __syncthreads();

  bf16x8 bfr3[2][3];
#pragma unroll
  for (int p = 0; p < 2; ++p)
#pragma unroll
    for (int ks = 0; ks < 3; ++ks)
      bfr3[p][ks] = *(bf16x8*)(&Att[w][(p * 16 + lo) * 96 + ks * 32 + hi * 8]);

  for (int cT = 0; cT < 32; ++cT) {
    f32x4 a0 = (f32x4){0.f, 0.f, 0.f, 0.f}, a1 = a0;
    const unsigned short* vr = vWt + (size_t)(cT * 16 + lo) * 96;
#pragma unroll
    for (int ks = 0; ks < 3; ++ks) {
      bf16x8 afr = *(const bf16x8*)(vr + ks * 32 + hi * 8);
      a0 = __builtin_amdgcn_mfma_f32_16x16x32_bf16(afr, bfr3[0][ks], a0, 0, 0, 0);
      a1 = __builtin_amdgcn_mfma_f32_16x16x32_bf16(afr, bfr3[1][ks], a1, 0, 0, 0);
    }
    f32x4 inv4 = *(f32x4*)(&bn_s[cT * 16 + hi * 4]);
    f32x4 add4 = *(f32x4*)(&bn_s[512 + cT * 16 + hi * 4]);
#pragma unroll
    for (int r = 0; r < 4; ++r) {
      int ch = cT * 16 + hi * 4 + r;
      float v0 = fmaxf(a0[r] * inv4[r] + add4[r], 0.f);
      float v1 = fmaxf(a1[r] * inv4[r] + add4[r], 0.f);
      size_t yb = (((size_t)(b * 512 + ch)) << 14) + pixbase;
      y[yb + lo] = v0;
      y[yb + 16 + lo] = v1;
    }
  }
}

// ---------------- host launch ----------------
extern "C" void kernel_launch(void* const* d_in, const int* in_sizes, int n_in,
                              void* d_out, int out_size, void* d_ws, size_t ws_size,
                              hipStream_t stream) {
  (void)in_sizes; (void)n_in; (void)out_size; (void)ws_size;
  const float* x     = (const float*)d_in[0];
  const float* sim   = (const float*)d_in[1];
  const float* g     = (const float*)d_in[2];
  const float* Wq    = (const float*)d_in[3];
  const float* bq    = (const float*)d_in[4];
  const float* Wk    = (const float*)d_in[5];
  const float* bk    = (const float*)d_in[6];
  const float* Wv    = (const float*)d_in[7];
  const float* bv    = (const float*)d_in[8];
  const float* Wc    = (const float*)d_in[9];
  const float* gamma = (const float*)d_in[10];
  const float* beta  = (const float*)d_in[11];
  const float* mean  = (const float*)d_in[12];
  const float* var   = (const float*)d_in[13];
  float* out = (float*)d_out;
  float* ws  = (float*)d_ws;
  float* y   = out;                    // [4][512][128][128]
  float* pcs = out + 33554432;         // [4][76][4][4]
  unsigned short* expsim  = (unsigned short*)(ws + OFF_EXPSIM);
  unsigned short* localbf = (unsigned short*)(ws + OFF_LOCALBF);
  unsigned short* Wqkt    = (unsigned short*)(ws + OFF_WQKT);
  unsigned short* vWt     = (unsigned short*)(ws + OFF_VWT);
  unsigned short* WqWkT   = (unsigned short*)(ws + OFF_WQWKT);
  unsigned short* WvWcT   = (unsigned short*)(ws + OFF_WVWCT);

  hipLaunchKernelGGL(kW_pre, dim3(65, 2), dim3(256), 0, stream,
                     Wq, Wk, Wv, Wc, bq, bk, gamma, beta, mean, var,
                     WqWkT, WvWcT, ws + OFF_WKBQ, ws + OFF_BQKADD,
                     ws + OFF_INV, ws + OFF_ADD, ws + OFF_CBB);
  hipLaunchKernelGGL(k1_stats, dim3(CMP_, 64), dim3(256), 0, stream,
                     sim, pcs, ws + OFF_CBB, expsim, ws + OFF_BK2);
  hipLaunchKernelGGL(k2_local, dim3(4, 64), dim3(512), 0, stream,
                     x, expsim, ws + OFF_WKBQ, localbf, ws + OFF_BK2);
  hipLaunchKernelGGL(k3n_wqkt, dim3(4, 64), dim3(256), 0, stream,
                     localbf, WqWkT, ws + OFF_BQKADD, Wqkt);
  hipLaunchKernelGGL(kV_vwt, dim3(8, 2), dim3(256), 0, stream,
                     WvWcT, g, bv, Wc, vWt);
  hipLaunchKernelGGL(k4_attn, dim3(8, 64), dim3(256), 0, stream,
                     x, Wqkt, ws + OFF_BK2, vWt,
                     ws + OFF_INV, ws + OFF_ADD, y);
}